// Round 6
// baseline (430.515 us; speedup 1.0000x reference)
//
#include <hip/hip_runtime.h>

#define NN 20000
#define NE 640000
#define HH 128
#define NBIN 16
#define RSQRT_H 0.08838834764831845f  /* 1/sqrt(128) */

typedef short bf16x8 __attribute__((ext_vector_type(8)));
typedef float f32x4 __attribute__((ext_vector_type(4)));

__device__ __forceinline__ float b2f(unsigned short u) {
    return __uint_as_float(((unsigned)u) << 16);
}
__device__ __forceinline__ unsigned short f2b(float f) {
    unsigned u = __float_as_uint(f);
    unsigned r = (u + 0x7fffu + ((u >> 16) & 1u)) >> 16;  // round-to-nearest-even
    return (unsigned short)r;
}
__device__ __forceinline__ int clampn(int v) {
    return min(max(v, 0), NN - 1);
}
__device__ __forceinline__ float dotdw(unsigned a, unsigned b) {
    float lo = __uint_as_float(a << 16) * __uint_as_float(b << 16);
    float hi = __uint_as_float(a & 0xffff0000u) * __uint_as_float(b & 0xffff0000u);
    return lo + hi;
}

// ---------------- fused prep: x->bf16 | ev | weights | cnt=0 ----------------
// block roles: [0,2500) prep_x, [2500,2579) ev, [2579,2707) prep_w, [2707,2786) zero cnt
__global__ __launch_bounds__(256) void k_prep(
    const float* __restrict__ x, ushort* __restrict__ xb,
    const int* __restrict__ ei, const float* __restrict__ pos, float4* __restrict__ ev4,
    const float* __restrict__ W1, const float* __restrict__ W2,
    const float* __restrict__ Wq, const float* __restrict__ Wk,
    ushort* __restrict__ W1T, ushort* __restrict__ W2T, ushort* __restrict__ WqkT,
    unsigned* __restrict__ cnt)
{
    const int bid = blockIdx.x, tid = threadIdx.x;
    if (bid < 2500) {                         // x -> bf16 (640000 float4 groups)
        int i = bid * 256 + tid;
        float4 v = ((const float4*)x)[i];
        ushort4 o;
        o.x = f2b(v.x); o.y = f2b(v.y); o.z = f2b(v.z); o.w = f2b(v.w);
        ((ushort4*)xb)[i] = o;
    } else if (bid < 2579) {                  // unit edge vectors, rows 0..NN-1
        int n = (bid - 2500) * 256 + tid;
        if (n < NN) {
            int s = clampn(ei[n]), d = clampn(ei[NE + n]);
            float dx = __fsub_rn(pos[d * 3 + 0], pos[s * 3 + 0]);
            float dy = __fsub_rn(pos[d * 3 + 1], pos[s * 3 + 1]);
            float dz = __fsub_rn(pos[d * 3 + 2], pos[s * 3 + 2]);
            float nsq = __fadd_rn(__fadd_rn(__fmul_rn(dx, dx), __fmul_rn(dy, dy)),
                                  __fmul_rn(dz, dz));
            float den = __fadd_rn(__fsqrt_rn(nsq), 1e-8f);
            float4 o;
            o.x = __fdiv_rn(dx, den); o.y = __fdiv_rn(dy, den);
            o.z = __fdiv_rn(dz, den); o.w = 0.f;
            ev4[n] = o;
        }
    } else if (bid < 2707) {                  // weights (transposed bf16)
        int i = (bid - 2579) * 256 + tid;     // 0..32767
        if (i < 128 * 256) {
            int c = i >> 8, k = i & 255;
            W1T[i] = f2b(W1[k * 128 + c]);
        }
        if (i < 128 * 128) {
            int c = i >> 7, k = i & 127;
            W2T[i] = f2b(W2[k * 128 + c]);
        }
        if (i < 256 * 128) {                  // cols 0..127 = Wq*scale, 128..255 = Wk
            int c = i >> 7, k = i & 127;
            float v = (c < 128) ? Wq[k * 128 + c] * RSQRT_H : Wk[k * 128 + (c - 128)];
            WqkT[i] = f2b(v);
        }
    } else {                                  // zero degree counters
        int i = (bid - 2707) * 256 + tid;
        if (i < NN) cnt[i] = 0u;
    }
}

// ---------------- fused MLP + q/k projection (rows 0..NN-1) ----------------
__global__ __launch_bounds__(256) void k_mlp(
    const int* __restrict__ ei, const ushort* __restrict__ xb,
    const ushort* __restrict__ W1T, const ushort* __restrict__ W2T,
    const ushort* __restrict__ WqkT,
    const float* __restrict__ b1, const float* __restrict__ b2,
    const float* __restrict__ bq, const float* __restrict__ bk,
    ushort* __restrict__ ebuf, ushort* __restrict__ qbuf, ushort* __restrict__ kbuf)
{
    __shared__ ushort A[64][264];        // 64 rows x 256 bf16 (+8 pad)
    __shared__ ushort T[4][16][136];     // per-wave t tile
    __shared__ ushort Eb[4][16][136];    // per-wave e tile
    __shared__ int SN[64], DN[64];

    const int tid = threadIdx.x;
    const int wave = tid >> 6, lane = tid & 63;
    const int rw = lane & 15, kq = lane >> 4;
    const int m0 = blockIdx.x * 64;

    if (tid < 64)        SN[tid]      = (m0 + tid < NN)      ? clampn(ei[m0 + tid]) : 0;
    else if (tid < 128)  DN[tid - 64] = (m0 + tid - 64 < NN) ? clampn(ei[NE + m0 + tid - 64]) : 0;
    __syncthreads();

    const unsigned* x32 = (const unsigned*)xb;
    #pragma unroll
    for (int it = 0; it < 32; ++it) {
        int flat = tid + 256 * it;       // 0..8191 (64 rows * 128 words)
        int r = flat >> 7, w = flat & 127;
        int node = (w < 64) ? SN[r] : DN[r];
        unsigned val = x32[node * 64 + (w & 63)];
        *(unsigned*)&A[r][2 * w] = val;
    }
    __syncthreads();

    // stage 1: t = silu(A @ W1 + b1)
    f32x4 acc[8];
    #pragma unroll
    for (int c = 0; c < 8; c++) acc[c] = (f32x4){0.f, 0.f, 0.f, 0.f};
    for (int k0 = 0; k0 < 256; k0 += 32) {
        bf16x8 a = *(const bf16x8*)&A[wave * 16 + rw][k0 + 8 * kq];
        #pragma unroll
        for (int c = 0; c < 8; c++) {
            bf16x8 b = *(const bf16x8*)&W1T[(c * 16 + rw) * 256 + k0 + 8 * kq];
            acc[c] = __builtin_amdgcn_mfma_f32_16x16x32_bf16(a, b, acc[c], 0, 0, 0);
        }
    }
    #pragma unroll
    for (int c = 0; c < 8; c++) {
        float bias = b1[c * 16 + rw];
        #pragma unroll
        for (int r = 0; r < 4; r++) {
            float v = acc[c][r] + bias;
            float s = v / (1.f + __expf(-v));   // silu
            T[wave][kq * 4 + r][c * 16 + rw] = f2b(s);
        }
    }
    __syncthreads();

    // stage 2: e = T @ W2 + b2
    f32x4 acc2[8];
    #pragma unroll
    for (int c = 0; c < 8; c++) acc2[c] = (f32x4){0.f, 0.f, 0.f, 0.f};
    for (int k0 = 0; k0 < 128; k0 += 32) {
        bf16x8 a = *(const bf16x8*)&T[wave][rw][k0 + 8 * kq];
        #pragma unroll
        for (int c = 0; c < 8; c++) {
            bf16x8 b = *(const bf16x8*)&W2T[(c * 16 + rw) * 128 + k0 + 8 * kq];
            acc2[c] = __builtin_amdgcn_mfma_f32_16x16x32_bf16(a, b, acc2[c], 0, 0, 0);
        }
    }
    #pragma unroll
    for (int c = 0; c < 8; c++) {
        float bias = b2[c * 16 + rw];
        #pragma unroll
        for (int r = 0; r < 4; r++) {
            float v = acc2[c][r] + bias;
            ushort hv = f2b(v);
            Eb[wave][kq * 4 + r][c * 16 + rw] = hv;
            int n = m0 + wave * 16 + kq * 4 + r;
            if (n < NN) ebuf[n * HH + c * 16 + rw] = hv;
        }
    }
    __syncthreads();

    // stage 3: [q|k] = Eb @ [Wq*s | Wk] + bias
    f32x4 acc3[16];
    #pragma unroll
    for (int c = 0; c < 16; c++) acc3[c] = (f32x4){0.f, 0.f, 0.f, 0.f};
    for (int k0 = 0; k0 < 128; k0 += 32) {
        bf16x8 a = *(const bf16x8*)&Eb[wave][rw][k0 + 8 * kq];
        #pragma unroll
        for (int c = 0; c < 16; c++) {
            bf16x8 b = *(const bf16x8*)&WqkT[(c * 16 + rw) * 128 + k0 + 8 * kq];
            acc3[c] = __builtin_amdgcn_mfma_f32_16x16x32_bf16(a, b, acc3[c], 0, 0, 0);
        }
    }
    #pragma unroll
    for (int c = 0; c < 16; c++) {
        int col = c * 16 + rw;
        float bias = (col < 128) ? bq[col] * RSQRT_H : bk[col - 128];
        #pragma unroll
        for (int r = 0; r < 4; r++) {
            float v = acc3[c][r] + bias;
            int n = m0 + wave * 16 + kq * 4 + r;
            if (n < NN) {
                if (col < 128) qbuf[n * HH + col] = f2b(v);
                else           kbuf[n * HH + col - 128] = f2b(v);
            }
        }
    }
}

// ---------------- degree histogram ----------------
__global__ void k_hist(const int* __restrict__ ei, unsigned* __restrict__ cnt) {
    int e = blockIdx.x * 256 + threadIdx.x;
    if (e < NE) atomicAdd(&cnt[clampn(ei[NE + e])], 1u);
}

// ---------------- exclusive scan of per-node degree (single block, LDS-staged) ----------------
__global__ __launch_bounds__(1024) void k_scan(const unsigned* __restrict__ cnt,
                                               unsigned* __restrict__ starts,
                                               unsigned* __restrict__ cursor) {
    __shared__ unsigned vals[20480];
    __shared__ unsigned wsum[16];
    const int t = threadIdx.x;
    #pragma unroll
    for (int i = 0; i < 20; i++) {
        int idx = i * 1024 + t;                       // coalesced
        vals[idx] = (idx < NN) ? cnt[idx] : 0u;
    }
    __syncthreads();
    const int base = t * 20;
    unsigned loc[20];
    unsigned s = 0;
    #pragma unroll
    for (int i = 0; i < 20; i++) { loc[i] = s; s += vals[base + i]; }
    const int lane = t & 63, wv = t >> 6;
    unsigned inc = s;
    #pragma unroll
    for (int o = 1; o < 64; o <<= 1) {
        unsigned y = __shfl_up(inc, o);
        if (lane >= o) inc += y;
    }
    if (lane == 63) wsum[wv] = inc;
    __syncthreads();
    unsigned wbase = 0;
    for (int i = 0; i < wv; i++) wbase += wsum[i];
    unsigned excl = wbase + inc - s;
    #pragma unroll
    for (int i = 0; i < 20; i++) {
        int idx = base + i;
        if (idx < NN) {
            unsigned val = excl + loc[i];
            starts[idx] = val;
            cursor[idx] = val;
        }
    }
    if (t == 1023) starts[NN] = wbase + inc;
}

// ---------------- per-edge: logit + bin + fused scatter of sorted metadata ----------------
__global__ __launch_bounds__(256) void k_edge(
    const int* __restrict__ ei, const ushort* __restrict__ qbuf,
    const ushort* __restrict__ kbuf, const float4* __restrict__ ev4,
    unsigned* __restrict__ cursor, uint2* __restrict__ sorted)
{
    int tid = blockIdx.x * 256 + threadIdx.x;
    int e = tid >> 2;            // 4 lanes per edge
    int r = tid & 3;
    if (e >= NE) return;
    int s = clampn(ei[e]), d = clampn(ei[NE + e]);

    const uint4* q4 = (const uint4*)qbuf;   // row = 16 uint4 (128 bf16)
    const uint4* k4 = (const uint4*)kbuf;
    float p = 0.f;
    #pragma unroll
    for (int i = 0; i < 4; i++) {
        uint4 qw = q4[d * 16 + r * 4 + i];
        uint4 kw = k4[s * 16 + r * 4 + i];
        p += dotdw(qw.x, kw.x) + dotdw(qw.y, kw.y) + dotdw(qw.z, kw.z) + dotdw(qw.w, kw.w);
    }
    p += __shfl_xor(p, 1);       // quad-local reduce
    p += __shfl_xor(p, 2);

    if (r == 0) {
        float4 vi = ev4[d], vj = ev4[s];
        float cosv = __fadd_rn(__fadd_rn(__fmul_rn(vi.x, vj.x), __fmul_rn(vi.y, vj.y)),
                               __fmul_rn(vi.z, vj.z));
        cosv = fminf(fmaxf(cosv, -1.f), 1.f);
        int cntb = 0;
        #pragma unroll
        for (int i = 0; i <= 16; i++) cntb += ((-1.f + 0.125f * (float)i) < cosv) ? 1 : 0;
        int b = min(max(cntb - 1, 0), NBIN - 1);
        unsigned pos = atomicAdd(&cursor[d], 1u);
        sorted[pos] = make_uint2(__float_as_uint(p), (unsigned)((s << 4) | b));
    }
}

// ---------------- per-node softmax+gather: one WAVE per node, REGISTER accumulators ----------------
__global__ __launch_bounds__(256) void k_node(
    const unsigned* __restrict__ starts, const uint2* __restrict__ sorted,
    const ushort* __restrict__ ebuf, float* __restrict__ out)
{
    const int wave = threadIdx.x >> 6, lane = threadIdx.x & 63;
    const int n = blockIdx.x * 4 + wave;     // NN = 20000 = 5000*4, exact
    __shared__ float den[4][NBIN];

    if (lane < NBIN) den[wave][lane] = 0.f;
    const unsigned s0 = starts[n];
    const int deg = (int)(starts[n + 1] - s0);

    // pass A: denominators (wave-private LDS atomics; |logit| small => no max-shift)
    for (int j0 = 0; j0 < deg; j0 += 64) {
        int j = j0 + lane;
        if (j < deg) {
            uint2 m = sorted[s0 + j];
            atomicAdd(&den[wave][m.y & 15u], __expf(__uint_as_float(m.x)));
        }
    }
    if (lane < NBIN) den[wave][lane] = 1.f / (den[wave][lane] + 1e-16f);

    // pass B: register accumulators; bin is wave-uniform => scalar switch, static reg index
    float accx[NBIN], accy[NBIN];
    #pragma unroll
    for (int i = 0; i < NBIN; i++) { accx[i] = 0.f; accy[i] = 0.f; }

    const unsigned* erow = (const unsigned*)ebuf;   // row = 64 uints (128 bf16)
    uint2 mN[4];
    #pragma unroll
    for (int i = 0; i < 4; i++)
        mN[i] = (i < deg) ? sorted[s0 + i] : make_uint2(0u, 0u);

#define ACC_CASE(K) case K: accx[K] += w * vx; accy[K] += w * vy; break;
    for (int jb = 0; jb < deg; jb += 4) {
        uint2 m[4];
        #pragma unroll
        for (int i = 0; i < 4; i++) m[i] = mN[i];
        #pragma unroll
        for (int i = 0; i < 4; i++) {
            int j = jb + 4 + i;
            mN[i] = (j < deg) ? sorted[s0 + j] : make_uint2(0u, 0u);
        }
        unsigned rv[4];
        #pragma unroll
        for (int i = 0; i < 4; i++)
            rv[i] = (jb + i < deg) ? erow[(m[i].y >> 4) * 64 + lane] : 0u;
        #pragma unroll
        for (int i = 0; i < 4; i++) {
            if (jb + i < deg) {          // wave-uniform branch
                int b = (int)__builtin_amdgcn_readfirstlane(m[i].y & 15u);
                float w = __expf(__uint_as_float(m[i].x)) * den[wave][b];
                float vx = w, vy = w;    // init to silence warnings; overwritten
                vx = b2f((unsigned short)(rv[i] & 0xffffu));
                vy = b2f((unsigned short)(rv[i] >> 16));
                switch (b) {
                    ACC_CASE(0) ACC_CASE(1) ACC_CASE(2) ACC_CASE(3)
                    ACC_CASE(4) ACC_CASE(5) ACC_CASE(6) ACC_CASE(7)
                    ACC_CASE(8) ACC_CASE(9) ACC_CASE(10) ACC_CASE(11)
                    ACC_CASE(12) ACC_CASE(13) ACC_CASE(14) ACC_CASE(15)
                }
            }
        }
    }
#undef ACC_CASE

    // output: lane owns features h=2*lane, 2*lane+1 => out[n][32*lane .. 32*lane+31] contiguous
    float* op = out + (size_t)n * (HH * NBIN) + 32 * lane;
    #pragma unroll
    for (int j = 0; j < 4; j++) {
        float4 o;
        o.x = accx[4 * j + 0]; o.y = accx[4 * j + 1];
        o.z = accx[4 * j + 2]; o.w = accx[4 * j + 3];
        ((float4*)op)[j] = o;
    }
    #pragma unroll
    for (int j = 0; j < 4; j++) {
        float4 o;
        o.x = accy[4 * j + 0]; o.y = accy[4 * j + 1];
        o.z = accy[4 * j + 2]; o.w = accy[4 * j + 3];
        ((float4*)op)[4 + j] = o;
    }
}

extern "C" void kernel_launch(void* const* d_in, const int* in_sizes, int n_in,
                              void* d_out, int out_size, void* d_ws, size_t ws_size,
                              hipStream_t stream) {
    const float* x        = (const float*)d_in[0];
    const float* pos      = (const float*)d_in[1];
    const int* ei         = (const int*)d_in[2];
    const float* W1       = (const float*)d_in[3];
    const float* b1       = (const float*)d_in[4];
    const float* W2       = (const float*)d_in[5];
    const float* b2       = (const float*)d_in[6];
    const float* Wq       = (const float*)d_in[7];
    const float* bq       = (const float*)d_in[8];
    const float* Wk       = (const float*)d_in[9];
    const float* bk       = (const float*)d_in[10];
    float* out = (float*)d_out;

    char* p = (char*)d_ws;
    auto take = [&](size_t bytes) -> char* {
        char* q = p;
        p += (bytes + 255) & ~(size_t)255;
        return q;
    };
    ushort* xb     = (ushort*)take((size_t)NN * HH * 2);
    ushort* ebuf   = (ushort*)take((size_t)NN * HH * 2);
    ushort* qbuf   = (ushort*)take((size_t)NN * HH * 2);
    ushort* kbuf   = (ushort*)take((size_t)NN * HH * 2);
    float4* ev4    = (float4*)take((size_t)NN * 16);
    ushort* W1T    = (ushort*)take(128 * 256 * 2);
    ushort* W2T    = (ushort*)take(128 * 128 * 2);
    ushort* WqkT   = (ushort*)take(256 * 128 * 2);
    unsigned* cnt  = (unsigned*)take((size_t)NN * 4);
    unsigned* starts = (unsigned*)take((size_t)(NN + 1) * 4);
    unsigned* cursor = (unsigned*)take((size_t)NN * 4);
    uint2* sorted  = (uint2*)take((size_t)NE * 8);
    if ((size_t)(p - (char*)d_ws) > ws_size) return;

    k_prep<<<2786, 256, 0, stream>>>(x, xb, ei, pos, ev4, W1, W2, Wq, Wk,
                                     W1T, W2T, WqkT, cnt);
    k_mlp<<<(NN + 63) / 64, 256, 0, stream>>>(ei, xb, W1T, W2T, WqkT, b1, b2, bq, bk,
                                              ebuf, qbuf, kbuf);
    k_hist<<<(NE + 255) / 256, 256, 0, stream>>>(ei, cnt);
    k_scan<<<1, 1024, 0, stream>>>(cnt, starts, cursor);
    k_edge<<<(NE * 4 + 255) / 256, 256, 0, stream>>>(ei, qbuf, kbuf, ev4, cursor, sorted);
    k_node<<<NN / 4, 256, 0, stream>>>(starts, sorted, ebuf, out);
}